// Round 1
// baseline (934.941 us; speedup 1.0000x reference)
//
#include <hip/hip_runtime.h>
#include <math.h>

#define DIM 768
#define HEADS 4
#define HDIM 3072   // HEADS*DIM
#define BATCH 128

// ---------------------------------------------------------------------------
// Generic GEMM: C[m][n] = sum_k A[m*lda+k] * B[n*ldb+k] (+ bias[n])
// A: M x K rows (lda), B: N x K rows (ldb)  [i.e. C = A @ B^T], C: ldc stride.
// grid.z = heads; per-head element offsets aOff/bOff/cOff applied to pointers.
// Tiles: BM=32, BN=64, BK=32; 256 threads; per-thread 4m x 2n register tile.
// ---------------------------------------------------------------------------
__global__ __launch_bounds__(256) void gemm_abt(
    const float* __restrict__ A, int lda, int aOff,
    const float* __restrict__ B, int ldb, int bOff,
    const float* __restrict__ bias,
    float* __restrict__ C, int ldc, int cOff,
    int M, int N, int K)
{
    __shared__ float As[32][36];   // [k][m], stride 36 keeps float4 16B-aligned
    __shared__ float Bs[32][66];   // [k][n], stride 66 keeps float2 8B-aligned

    const int h = blockIdx.z;
    A += (long)h * aOff;
    B += (long)h * bOff;
    C += (long)h * cOff;

    const int tid = threadIdx.x;
    const int m0 = blockIdx.y * 32;
    const int n0 = blockIdx.x * 64;
    const int tx = tid & 31;    // n pair index: n = tx*2, tx*2+1
    const int ty = tid >> 5;    // 0..7 : m = ty*4 .. ty*4+3

    float acc[4][2];
#pragma unroll
    for (int i = 0; i < 4; ++i) { acc[i][0] = 0.f; acc[i][1] = 0.f; }

    const int lk = tid & 31;    // k-col for staging loads
    const int lm = tid >> 5;    // 0..7

    for (int k0 = 0; k0 < K; k0 += 32) {
        // stage A tile (32 rows x 32 k) transposed -> As[k][m]
#pragma unroll
        for (int r = 0; r < 4; ++r) {
            int m = lm + r * 8;
            float v = 0.f;
            if (m0 + m < M) v = A[(long)(m0 + m) * lda + k0 + lk];
            As[lk][m] = v;
        }
        // stage B tile (64 rows x 32 k) transposed -> Bs[k][n]
#pragma unroll
        for (int r = 0; r < 8; ++r) {
            int n = lm + r * 8;
            Bs[lk][n] = B[(long)(n0 + n) * ldb + k0 + lk];
        }
        __syncthreads();
#pragma unroll
        for (int kk = 0; kk < 32; ++kk) {
            float4 a4 = *(const float4*)&As[kk][ty * 4];
            float2 b2 = *(const float2*)&Bs[kk][tx * 2];
            const float* ap = (const float*)&a4;
#pragma unroll
            for (int i = 0; i < 4; ++i) {
                acc[i][0] += ap[i] * b2.x;
                acc[i][1] += ap[i] * b2.y;
            }
        }
        __syncthreads();
    }

    const int n = n0 + tx * 2;
    float bx = 0.f, by = 0.f;
    if (bias) { bx = bias[n]; by = bias[n + 1]; }
#pragma unroll
    for (int i = 0; i < 4; ++i) {
        int m = m0 + ty * 4 + i;
        if (m < M) {
            float2 o;
            o.x = acc[i][0] + bx;
            o.y = acc[i][1] + by;
            *(float2*)&C[(long)m * ldc + n] = o;
        }
    }
}

// ---------------------------------------------------------------------------
// Per-(batch,token) pair kernel: attention row 0 + FC combine + 2x LN + score
// One 256-thread block per pair. wave w handles head w for the dot products.
// ---------------------------------------------------------------------------
__device__ inline void block_reduce2(float& a, float& b, float* redA, float* redB, int tid)
{
    int lane = tid & 63, wave = tid >> 6;
#pragma unroll
    for (int off = 32; off; off >>= 1) {
        a += __shfl_down(a, off);
        b += __shfl_down(b, off);
    }
    if (lane == 0) { redA[wave] = a; redB[wave] = b; }
    __syncthreads();
    a = redA[0] + redA[1] + redA[2] + redA[3];
    b = redB[0] + redB[1] + redB[2] + redB[3];
    __syncthreads();   // allow scratch reuse
}

__global__ __launch_bounds__(256) void score_kernel(
    const float* __restrict__ tok_q,   // T x 3072
    const float* __restrict__ tok_k,   // T x 3072
    const float* __restrict__ k_task,  // 128 x 3072
    const float* __restrict__ U_tok,   // T x 3072   (head-blocked fc(v_tok))
    const float* __restrict__ U_task,  // 128 x 3072 (head-blocked fc(v_task))
    const float* __restrict__ tokens,  // T x 768
    const float* __restrict__ fcb,     // 768
    const float* __restrict__ lng, const float* __restrict__ lnb,
    const float* __restrict__ slng, const float* __restrict__ slnb,
    const float* __restrict__ sw, const float* __restrict__ sbias,
    float* __restrict__ out,           // 128 x 80
    int T, int outOff)
{
    const int bid = blockIdx.x;
    const int b = bid / T;
    const int t = bid - b * T;
    const int tid = threadIdx.x;
    const int lane = tid & 63;
    const int wave = tid >> 6;   // == head

    __shared__ float coef[HEADS][2];
    __shared__ float redA[4], redB[4];

    // ---- step 1: per-head attention row-0 softmax weights ----
    {
        const float* q  = tok_q  + (long)t * HDIM + wave * DIM;
        const float* kt = tok_k  + (long)t * HDIM + wave * DIM;
        const float* kb = k_task + (long)b * HDIM + wave * DIM;
        float s00 = 0.f, s01 = 0.f;
        for (int d = lane; d < DIM; d += 64) {
            float qv = q[d];
            s00 += qv * kt[d];
            s01 += qv * kb[d];
        }
#pragma unroll
        for (int off = 32; off; off >>= 1) {
            s00 += __shfl_down(s00, off);
            s01 += __shfl_down(s01, off);
        }
        if (lane == 0) {
            const float scale = 0.03608439182435161f;  // 1/sqrt(768)
            float x0 = s00 * scale, x1 = s01 * scale;
            float mx = fmaxf(x0, x1);
            float e0 = expf(x0 - mx), e1 = expf(x1 - mx);
            float inv = 1.f / (e0 + e1);
            coef[wave][0] = e0 * inv;
            coef[wave][1] = e1 * inv;
        }
    }
    __syncthreads();

    const float c00 = coef[0][0], c01 = coef[0][1];
    const float c10 = coef[1][0], c11 = coef[1][1];
    const float c20 = coef[2][0], c21 = coef[2][1];
    const float c30 = coef[3][0], c31 = coef[3][1];

    // ---- step 2: r = fc(o0) + fcb + x0 ;  3 elements per thread ----
    float r[3];
    float sum = 0.f, sq = 0.f;
    const float* Ut = U_tok  + (long)t * HDIM;
    const float* Ub = U_task + (long)b * HDIM;
#pragma unroll
    for (int j = 0; j < 3; ++j) {
        int d = tid + j * 256;
        float v = fcb[d] + tokens[(long)t * DIM + d];
        v += c00 * Ut[d]           + c01 * Ub[d];
        v += c10 * Ut[DIM + d]     + c11 * Ub[DIM + d];
        v += c20 * Ut[2 * DIM + d] + c21 * Ub[2 * DIM + d];
        v += c30 * Ut[3 * DIM + d] + c31 * Ub[3 * DIM + d];
        r[j] = v;
        sum += v;
        sq += v * v;
    }
    block_reduce2(sum, sq, redA, redB, tid);
    float mean = sum * (1.f / DIM);
    float var = sq * (1.f / DIM) - mean * mean;
    float inv = rsqrtf(var + 1e-5f);

    // ---- LN1 ----
    float y[3];
    float sum2 = 0.f, sq2 = 0.f;
#pragma unroll
    for (int j = 0; j < 3; ++j) {
        int d = tid + j * 256;
        float v = (r[j] - mean) * inv * lng[d] + lnb[d];
        y[j] = v;
        sum2 += v;
        sq2 += v * v;
    }
    block_reduce2(sum2, sq2, redA, redB, tid);
    float mean2 = sum2 * (1.f / DIM);
    float var2 = sq2 * (1.f / DIM) - mean2 * mean2;
    float inv2 = rsqrtf(var2 + 1e-5f);

    // ---- LN2 + score dot ----
    float partial = 0.f, dummy = 0.f;
#pragma unroll
    for (int j = 0; j < 3; ++j) {
        int d = tid + j * 256;
        float c = (y[j] - mean2) * inv2 * slng[d] + slnb[d];
        partial += c * sw[d];
    }
    block_reduce2(partial, dummy, redA, redB, tid);
    if (tid == 0) out[(long)b * 80 + outOff + t] = partial + sbias[0];
}

// ---------------------------------------------------------------------------
extern "C" void kernel_launch(void* const* d_in, const int* in_sizes, int n_in,
                              void* d_out, int out_size, void* d_ws, size_t ws_size,
                              hipStream_t stream)
{
    const float* task_emb    = (const float*)d_in[0];   // 128 x 768
    const float* tokens_l1   = (const float*)d_in[1];   // 16 x 768
    const float* tokens_l2   = (const float*)d_in[2];   // 64 x 768
    const float* task_proj_w = (const float*)d_in[3];   // 768 x 768
    const float* task_proj_b = (const float*)d_in[4];   // 768

    float* out = (float*)d_out;

    // workspace layout (floats)
    float* ws = (float*)d_ws;
    float* task_p = ws;                    // 128*768   = 98304
    float* tok_q  = task_p + 98304;        // 64*3072   = 196608 (max T)
    float* tok_k  = tok_q + 196608;
    float* tok_v  = tok_k + 196608;
    float* U_tok  = tok_v + 196608;
    float* k_task = U_tok + 196608;        // 128*3072  = 393216
    float* v_task = k_task + 393216;
    float* U_task = v_task + 393216;

    dim3 blk(256);

    // task_p = task_emb @ task_proj_w.T + task_proj_b   (128 x 768)
    gemm_abt<<<dim3(12, 4, 1), blk, 0, stream>>>(
        task_emb, DIM, 0, task_proj_w, DIM, 0, task_proj_b,
        task_p, DIM, 0, BATCH, DIM, DIM);

    auto run_level = [&](const float* tokens, int T, int outOff,
                         const float* wq, const float* wk, const float* wv,
                         const float* fcw, const float* fcb,
                         const float* lng, const float* lnb,
                         const float* slng, const float* slnb,
                         const float* sw, const float* sb) {
        int mt = (T + 31) / 32;
        // token projections: T x 3072
        gemm_abt<<<dim3(48, mt, 1), blk, 0, stream>>>(
            tokens, DIM, 0, wq, DIM, 0, nullptr, tok_q, HDIM, 0, T, HDIM, DIM);
        gemm_abt<<<dim3(48, mt, 1), blk, 0, stream>>>(
            tokens, DIM, 0, wk, DIM, 0, nullptr, tok_k, HDIM, 0, T, HDIM, DIM);
        gemm_abt<<<dim3(48, mt, 1), blk, 0, stream>>>(
            tokens, DIM, 0, wv, DIM, 0, nullptr, tok_v, HDIM, 0, T, HDIM, DIM);
        // task projections: 128 x 3072 (k and v only; q_task never needed)
        gemm_abt<<<dim3(48, 4, 1), blk, 0, stream>>>(
            task_p, DIM, 0, wk, DIM, 0, nullptr, k_task, HDIM, 0, BATCH, HDIM, DIM);
        gemm_abt<<<dim3(48, 4, 1), blk, 0, stream>>>(
            task_p, DIM, 0, wv, DIM, 0, nullptr, v_task, HDIM, 0, BATCH, HDIM, DIM);
        // U_task[b, h*768+d] = sum_e v_task[b, h*768+e] * fcw[d, h*768+e]
        gemm_abt<<<dim3(12, 4, HEADS), blk, 0, stream>>>(
            v_task, HDIM, DIM, fcw, HDIM, DIM, nullptr,
            U_task, HDIM, DIM, BATCH, DIM, DIM);
        // U_tok[t, h*768+d]
        gemm_abt<<<dim3(12, mt, HEADS), blk, 0, stream>>>(
            tok_v, HDIM, DIM, fcw, HDIM, DIM, nullptr,
            U_tok, HDIM, DIM, T, DIM, DIM);
        // fused attention row-0 + FC + LN + LN + score
        score_kernel<<<dim3(BATCH * T), blk, 0, stream>>>(
            tok_q, tok_k, k_task, U_tok, U_task, tokens, fcb,
            lng, lnb, slng, slnb, sw, sb, out, T, outOff);
    };

    // level 1: T=16, output cols [0,16)
    run_level(tokens_l1, 16, 0,
              (const float*)d_in[5], (const float*)d_in[6], (const float*)d_in[7],
              (const float*)d_in[8], (const float*)d_in[9],
              (const float*)d_in[10], (const float*)d_in[11],
              (const float*)d_in[12], (const float*)d_in[13],
              (const float*)d_in[14], (const float*)d_in[15]);
    // level 2: T=64, output cols [16,80)
    run_level(tokens_l2, 64, 16,
              (const float*)d_in[16], (const float*)d_in[17], (const float*)d_in[18],
              (const float*)d_in[19], (const float*)d_in[20],
              (const float*)d_in[21], (const float*)d_in[22],
              (const float*)d_in[23], (const float*)d_in[24],
              (const float*)d_in[25], (const float*)d_in[26]);
}

// Round 2
// 394.064 us; speedup vs baseline: 2.3726x; 2.3726x over previous
//
#include <hip/hip_runtime.h>
#include <math.h>

#define DIM 768
#define HEADS 4
#define HDIM 3072   // HEADS*DIM
#define BATCH 128

// ---------------------------------------------------------------------------
// Batched GEMM: several independent C = A @ B^T (+bias) sub-problems in ONE
// dispatch, described by a descriptor table passed by value in kernarg space.
// Tile: BM=32, BN=64, BK=32; 256 threads; per-thread 4m x 2n register tile.
// Rationale (R1): round-0 profile showed Occupancy 2%, VALUBusy 2.3% — each
// small GEMM starved the chip and 17 launches serialized. Batching gives each
// dispatch 400-1300 blocks.
// ---------------------------------------------------------------------------
struct GemmDesc {
    const float* A;   // M x K, row stride lda
    const float* B;   // N x K, row stride ldb
    const float* bias;
    float* C;         // M x N, row stride ldc
    int lda, ldb, ldc;
    int M, N, K;
    int blockBase;    // first (1-D) block id of this sub-problem
    int nTiles;       // N/64
    int pad;
};
#define MAXD 12
struct GemmBatch { GemmDesc d[MAXD]; int nDesc; };

__global__ __launch_bounds__(256) void gemm_batch(GemmBatch batch)
{
    __shared__ float As[32][36];   // [k][m], pad keeps float4 16B-aligned
    __shared__ float Bs[32][66];   // [k][n], pad keeps float2 8B-aligned

    // descriptor lookup (scalar, once per block)
    int bid = blockIdx.x;
    int i = 0;
    while (i + 1 < batch.nDesc && bid >= batch.d[i + 1].blockBase) ++i;
    const GemmDesc g = batch.d[i];
    int lb = bid - g.blockBase;
    int mt = lb / g.nTiles;
    int nt = lb - mt * g.nTiles;

    const float* __restrict__ A = g.A;
    const float* __restrict__ B = g.B;
    const int lda = g.lda, ldb = g.ldb;
    const int M = g.M, K = g.K;

    const int tid = threadIdx.x;
    const int m0 = mt * 32;
    const int n0 = nt * 64;
    const int tx = tid & 31;    // n pair index: n = tx*2, tx*2+1
    const int ty = tid >> 5;    // 0..7 : m = ty*4 .. ty*4+3

    float acc[4][2];
#pragma unroll
    for (int q = 0; q < 4; ++q) { acc[q][0] = 0.f; acc[q][1] = 0.f; }

    const int lk = tid & 31;    // k-col for staging loads
    const int lm = tid >> 5;    // 0..7

    for (int k0 = 0; k0 < K; k0 += 32) {
        // stage A tile (32 m x 32 k) transposed -> As[k][m]
#pragma unroll
        for (int r = 0; r < 4; ++r) {
            int m = lm + r * 8;
            float v = 0.f;
            if (m0 + m < M) v = A[(long)(m0 + m) * lda + k0 + lk];
            As[lk][m] = v;
        }
        // stage B tile (64 n x 32 k) transposed -> Bs[k][n]
#pragma unroll
        for (int r = 0; r < 8; ++r) {
            int n = lm + r * 8;
            Bs[lk][n] = B[(long)(n0 + n) * ldb + k0 + lk];
        }
        __syncthreads();
#pragma unroll
        for (int kk = 0; kk < 32; ++kk) {
            float4 a4 = *(const float4*)&As[kk][ty * 4];
            float2 b2 = *(const float2*)&Bs[kk][tx * 2];
            const float* ap = (const float*)&a4;
#pragma unroll
            for (int q = 0; q < 4; ++q) {
                acc[q][0] += ap[q] * b2.x;
                acc[q][1] += ap[q] * b2.y;
            }
        }
        __syncthreads();
    }

    const int n = n0 + tx * 2;
    float bx = 0.f, by = 0.f;
    if (g.bias) { bx = g.bias[n]; by = g.bias[n + 1]; }
#pragma unroll
    for (int q = 0; q < 4; ++q) {
        int m = m0 + ty * 4 + q;
        if (m < M) {
            float2 o;
            o.x = acc[q][0] + bx;
            o.y = acc[q][1] + by;
            *(float2*)&g.C[(long)m * g.ldc + n] = o;
        }
    }
}

// ---------------------------------------------------------------------------
// Per-(batch,token) pair kernel: attention row 0 + FC combine + 2x LN + score
// One 256-thread block per pair. wave w handles head w for the dot products.
// ---------------------------------------------------------------------------
__device__ inline void block_reduce2(float& a, float& b, float* redA, float* redB, int tid)
{
    int lane = tid & 63, wave = tid >> 6;
#pragma unroll
    for (int off = 32; off; off >>= 1) {
        a += __shfl_down(a, off);
        b += __shfl_down(b, off);
    }
    if (lane == 0) { redA[wave] = a; redB[wave] = b; }
    __syncthreads();
    a = redA[0] + redA[1] + redA[2] + redA[3];
    b = redB[0] + redB[1] + redB[2] + redB[3];
    __syncthreads();   // allow scratch reuse
}

__global__ __launch_bounds__(256) void score_kernel(
    const float* __restrict__ tok_q,   // T x 3072
    const float* __restrict__ tok_k,   // T x 3072
    const float* __restrict__ k_task,  // 128 x 3072
    const float* __restrict__ U_tok,   // T x 3072   (head-blocked fc(v_tok))
    const float* __restrict__ U_task,  // 128 x 3072 (head-blocked fc(v_task))
    const float* __restrict__ tokens,  // T x 768
    const float* __restrict__ fcb,     // 768
    const float* __restrict__ lng, const float* __restrict__ lnb,
    const float* __restrict__ slng, const float* __restrict__ slnb,
    const float* __restrict__ sw, const float* __restrict__ sbias,
    float* __restrict__ out,           // 128 x 80
    int T, int outOff)
{
    const int bid = blockIdx.x;
    const int b = bid / T;
    const int t = bid - b * T;
    const int tid = threadIdx.x;
    const int lane = tid & 63;
    const int wave = tid >> 6;   // == head

    __shared__ float coef[HEADS][2];
    __shared__ float redA[4], redB[4];

    // ---- step 1: per-head attention row-0 softmax weights ----
    {
        const float* q  = tok_q  + (long)t * HDIM + wave * DIM;
        const float* kt = tok_k  + (long)t * HDIM + wave * DIM;
        const float* kb = k_task + (long)b * HDIM + wave * DIM;
        float s00 = 0.f, s01 = 0.f;
        for (int d = lane; d < DIM; d += 64) {
            float qv = q[d];
            s00 += qv * kt[d];
            s01 += qv * kb[d];
        }
#pragma unroll
        for (int off = 32; off; off >>= 1) {
            s00 += __shfl_down(s00, off);
            s01 += __shfl_down(s01, off);
        }
        if (lane == 0) {
            const float scale = 0.03608439182435161f;  // 1/sqrt(768)
            float x0 = s00 * scale, x1 = s01 * scale;
            float mx = fmaxf(x0, x1);
            float e0 = expf(x0 - mx), e1 = expf(x1 - mx);
            float inv = 1.f / (e0 + e1);
            coef[wave][0] = e0 * inv;
            coef[wave][1] = e1 * inv;
        }
    }
    __syncthreads();

    const float c00 = coef[0][0], c01 = coef[0][1];
    const float c10 = coef[1][0], c11 = coef[1][1];
    const float c20 = coef[2][0], c21 = coef[2][1];
    const float c30 = coef[3][0], c31 = coef[3][1];

    // ---- step 2: r = fc(o0) + fcb + x0 ;  3 elements per thread ----
    float r[3];
    float sum = 0.f, sq = 0.f;
    const float* Ut = U_tok  + (long)t * HDIM;
    const float* Ub = U_task + (long)b * HDIM;
#pragma unroll
    for (int j = 0; j < 3; ++j) {
        int d = tid + j * 256;
        float v = fcb[d] + tokens[(long)t * DIM + d];
        v += c00 * Ut[d]           + c01 * Ub[d];
        v += c10 * Ut[DIM + d]     + c11 * Ub[DIM + d];
        v += c20 * Ut[2 * DIM + d] + c21 * Ub[2 * DIM + d];
        v += c30 * Ut[3 * DIM + d] + c31 * Ub[3 * DIM + d];
        r[j] = v;
        sum += v;
        sq += v * v;
    }
    block_reduce2(sum, sq, redA, redB, tid);
    float mean = sum * (1.f / DIM);
    float var = sq * (1.f / DIM) - mean * mean;
    float inv = rsqrtf(var + 1e-5f);

    // ---- LN1 ----
    float y[3];
    float sum2 = 0.f, sq2 = 0.f;
#pragma unroll
    for (int j = 0; j < 3; ++j) {
        int d = tid + j * 256;
        float v = (r[j] - mean) * inv * lng[d] + lnb[d];
        y[j] = v;
        sum2 += v;
        sq2 += v * v;
    }
    block_reduce2(sum2, sq2, redA, redB, tid);
    float mean2 = sum2 * (1.f / DIM);
    float var2 = sq2 * (1.f / DIM) - mean2 * mean2;
    float inv2 = rsqrtf(var2 + 1e-5f);

    // ---- LN2 + score dot ----
    float partial = 0.f, dummy = 0.f;
#pragma unroll
    for (int j = 0; j < 3; ++j) {
        int d = tid + j * 256;
        float c = (y[j] - mean2) * inv2 * slng[d] + slnb[d];
        partial += c * sw[d];
    }
    block_reduce2(partial, dummy, redA, redB, tid);
    if (tid == 0) out[(long)b * 80 + outOff + t] = partial + sbias[0];
}

// ---------------------------------------------------------------------------
extern "C" void kernel_launch(void* const* d_in, const int* in_sizes, int n_in,
                              void* d_out, int out_size, void* d_ws, size_t ws_size,
                              hipStream_t stream)
{
    const float* task_emb    = (const float*)d_in[0];   // 128 x 768
    const float* tokens_l1   = (const float*)d_in[1];   // 16 x 768
    const float* tokens_l2   = (const float*)d_in[2];   // 64 x 768
    const float* task_proj_w = (const float*)d_in[3];   // 768 x 768
    const float* task_proj_b = (const float*)d_in[4];   // 768

    const float* wq1  = (const float*)d_in[5];
    const float* wk1  = (const float*)d_in[6];
    const float* wv1  = (const float*)d_in[7];
    const float* fcw1 = (const float*)d_in[8];
    const float* fcb1 = (const float*)d_in[9];
    const float* lng1 = (const float*)d_in[10];
    const float* lnb1 = (const float*)d_in[11];
    const float* slng1= (const float*)d_in[12];
    const float* slnb1= (const float*)d_in[13];
    const float* sw1  = (const float*)d_in[14];
    const float* sb1  = (const float*)d_in[15];

    const float* wq2  = (const float*)d_in[16];
    const float* wk2  = (const float*)d_in[17];
    const float* wv2  = (const float*)d_in[18];
    const float* fcw2 = (const float*)d_in[19];
    const float* fcb2 = (const float*)d_in[20];
    const float* lng2 = (const float*)d_in[21];
    const float* lnb2 = (const float*)d_in[22];
    const float* slng2= (const float*)d_in[23];
    const float* slnb2= (const float*)d_in[24];
    const float* sw2  = (const float*)d_in[25];
    const float* sb2  = (const float*)d_in[26];

    float* out = (float*)d_out;

    // workspace layout (floats) — both levels live simultaneously now
    float* ws = (float*)d_ws;
    float* task_p   = ws;                      //  98304
    float* tq1      = task_p   +  98304;       //  16*3072 = 49152
    float* tk1      = tq1      +  49152;
    float* tv1      = tk1      +  49152;
    float* ut1      = tv1      +  49152;       // U_tok L1
    float* tq2      = ut1      +  49152;       //  64*3072 = 196608
    float* tk2      = tq2      + 196608;
    float* tv2      = tk2      + 196608;
    float* ut2      = tv2      + 196608;       // U_tok L2
    float* ktask1   = ut2      + 196608;       // 128*3072 = 393216
    float* vtask1   = ktask1   + 393216;
    float* utask1   = vtask1   + 393216;
    float* ktask2   = utask1   + 393216;
    float* vtask2   = ktask2   + 393216;
    float* utask2   = vtask2   + 393216;       // total ~3.44M floats = 13.8 MB

    auto mkDesc = [](const float* A, int lda, const float* B, int ldb,
                     const float* bias, float* C, int ldc,
                     int M, int N, int K, int base) {
        GemmDesc g;
        g.A = A; g.B = B; g.bias = bias; g.C = C;
        g.lda = lda; g.ldb = ldb; g.ldc = ldc;
        g.M = M; g.N = N; g.K = K;
        g.blockBase = base; g.nTiles = N / 64; g.pad = 0;
        return g;
    };
    auto blocksOf = [](int M, int N) { return ((M + 31) / 32) * (N / 64); };

    // ---- stage A: task_p + token q/k/v projections (7 descs, 480 blocks) ----
    {
        GemmBatch ba; int base = 0, nd = 0;
        ba.d[nd++] = mkDesc(task_emb, DIM, task_proj_w, DIM, task_proj_b,
                            task_p, DIM, BATCH, DIM, DIM, base);
        base += blocksOf(BATCH, DIM);
        const float* tA[2] = { tokens_l1, tokens_l2 };
        int tT[2] = { 16, 64 };
        const float* tW[2][3] = { { wq1, wk1, wv1 }, { wq2, wk2, wv2 } };
        float* tC[2][3] = { { tq1, tk1, tv1 }, { tq2, tk2, tv2 } };
        for (int l = 0; l < 2; ++l)
            for (int w = 0; w < 3; ++w) {
                ba.d[nd++] = mkDesc(tA[l], DIM, tW[l][w], DIM, nullptr,
                                    tC[l][w], HDIM, tT[l], HDIM, DIM, base);
                base += blocksOf(tT[l], HDIM);
            }
        ba.nDesc = nd;
        gemm_batch<<<dim3(base), dim3(256), 0, stream>>>(ba);
    }

    // ---- stage B: k_task/v_task both levels + U_tok per head (12 descs, 912 blocks) ----
    {
        GemmBatch bb; int base = 0, nd = 0;
        const float* kw[2] = { wk1, wk2 };
        const float* vw[2] = { wv1, wv2 };
        float* kc[2] = { ktask1, ktask2 };
        float* vc[2] = { vtask1, vtask2 };
        for (int l = 0; l < 2; ++l) {
            bb.d[nd++] = mkDesc(task_p, DIM, kw[l], DIM, nullptr,
                                kc[l], HDIM, BATCH, HDIM, DIM, base);
            base += blocksOf(BATCH, HDIM);
            bb.d[nd++] = mkDesc(task_p, DIM, vw[l], DIM, nullptr,
                                vc[l], HDIM, BATCH, HDIM, DIM, base);
            base += blocksOf(BATCH, HDIM);
        }
        const float* fw[2] = { fcw1, fcw2 };
        float* tv[2] = { tv1, tv2 };
        float* ut[2] = { ut1, ut2 };
        int tT[2] = { 16, 64 };
        for (int l = 0; l < 2; ++l)
            for (int h = 0; h < HEADS; ++h) {
                bb.d[nd++] = mkDesc(tv[l] + h * DIM, HDIM, fw[l] + h * DIM, HDIM,
                                    nullptr, ut[l] + h * DIM, HDIM,
                                    tT[l], DIM, DIM, base);
                base += blocksOf(tT[l], DIM);
            }
        bb.nDesc = nd;
        gemm_batch<<<dim3(base), dim3(256), 0, stream>>>(bb);
    }

    // ---- stage C: U_task per head per level (8 descs, 384 blocks) ----
    {
        GemmBatch bc; int base = 0, nd = 0;
        const float* fw[2] = { fcw1, fcw2 };
        float* vt[2] = { vtask1, vtask2 };
        float* utk[2] = { utask1, utask2 };
        for (int l = 0; l < 2; ++l)
            for (int h = 0; h < HEADS; ++h) {
                bc.d[nd++] = mkDesc(vt[l] + h * DIM, HDIM, fw[l] + h * DIM, HDIM,
                                    nullptr, utk[l] + h * DIM, HDIM,
                                    BATCH, DIM, DIM, base);
                base += blocksOf(BATCH, DIM);
            }
        bc.nDesc = nd;
        gemm_batch<<<dim3(base), dim3(256), 0, stream>>>(bc);
    }

    // ---- stage D/E: fused attention + LN + score, one block per (b,t) ----
    score_kernel<<<dim3(BATCH * 16), dim3(256), 0, stream>>>(
        tq1, tk1, ktask1, ut1, utask1, tokens_l1, fcb1,
        lng1, lnb1, slng1, slnb1, sw1, sb1, out, 16, 0);
    score_kernel<<<dim3(BATCH * 64), dim3(256), 0, stream>>>(
        tq2, tk2, ktask2, ut2, utask2, tokens_l2, fcb2,
        lng2, lnb2, slng2, slnb2, sw2, sb2, out, 64, 16);
}